// Round 1
// baseline (8095.612 us; speedup 1.0000x reference)
//
#include <hip/hip_runtime.h>

#define DIM   256
#define NVEC  8192
#define NCODE 8192
#define DEPTH 4

#define BM 128
#define BN 128
#define DC 16
#define KSPLIT 4
#define KPER (NCODE / KSPLIT)   // 2048 codes per split

// ---------------------------------------------------------------------------
// Kernel 1: per-row squared norms of all 4 codebooks. One wave per row.
// ---------------------------------------------------------------------------
__global__ __launch_bounds__(256) void prep_cc(const float* __restrict__ cb_all,
                                               float* __restrict__ cc) {
    int row  = blockIdx.x * 4 + (threadIdx.x >> 6);   // DEPTH*NCODE rows
    int lane = threadIdx.x & 63;
    float4 v = *(const float4*)&cb_all[row * DIM + lane * 4];
    float s = v.x * v.x + v.y * v.y + v.z * v.z + v.w * v.w;
    #pragma unroll
    for (int off = 32; off > 0; off >>= 1) s += __shfl_down(s, off, 64);
    if (lane == 0) cc[row] = s;
}

// ---------------------------------------------------------------------------
// Kernel 2: resid = x  (resid lives in the quants region of d_out)
// ---------------------------------------------------------------------------
__global__ __launch_bounds__(256) void init_resid(const float* __restrict__ x,
                                                  float* __restrict__ resid) {
    int i = blockIdx.x * blockDim.x + threadIdx.x;   // float4 index
    *(float4*)&resid[i * 4] = *(const float4*)&x[i * 4];
}

// ---------------------------------------------------------------------------
// Kernel 3: fused distance-GEMM + argmin over a K-split.
// score[n][k] = ||c_k||^2 - 2 * resid_n . c_k   (row-constant ||v||^2 dropped)
// grid = (NVEC/BM) * KSPLIT blocks of 256 threads.
// Thread (tr = t>>4, tc = t&15) owns rows {r*16+tr} and cols {c*16+tc},
// r,c in 0..7 (stride-16 mapping keeps LDS b128 reads conflict-free).
// ---------------------------------------------------------------------------
__global__ __launch_bounds__(256, 2) void argmin_kernel(
    const float* __restrict__ resid,  // [NVEC][DIM]
    const float* __restrict__ cb,     // [NCODE][DIM] (this depth)
    const float* __restrict__ ccn,    // [NCODE]
    float* __restrict__ pval,         // [NVEC][KSPLIT]
    int*   __restrict__ pidx) {
    __shared__ float As[BM][DC + 4];
    __shared__ float Bs[BN][DC + 4];
    __shared__ float redv[BM][16];
    __shared__ int   redi[BM][16];

    const int t     = threadIdx.x;
    const int mblk  = blockIdx.x / KSPLIT;
    const int split = blockIdx.x % KSPLIT;
    const int m0    = mblk * BM;
    const int tr    = t >> 4;
    const int tc    = t & 15;

    float best[8];
    int   bidx[8];
    #pragma unroll
    for (int r = 0; r < 8; ++r) { best[r] = 3.4e38f; bidx[r] = 0; }

    for (int kt = 0; kt < KPER / BN; ++kt) {           // ascending k tiles
        const int k0 = split * KPER + kt * BN;
        float acc[8][8];
        #pragma unroll
        for (int r = 0; r < 8; ++r)
            #pragma unroll
            for (int c = 0; c < 8; ++c) acc[r][c] = 0.f;

        for (int dt = 0; dt < DIM / DC; ++dt) {
            __syncthreads();   // protect previous iteration's reads
            #pragma unroll
            for (int u = 0; u < 2; ++u) {
                int id = t + u * 256;          // 0..511 float4 slots
                int r  = id >> 2, q = id & 3;
                *(float4*)&As[r][q * 4] =
                    *(const float4*)&resid[(m0 + r) * DIM + dt * DC + q * 4];
                *(float4*)&Bs[r][q * 4] =
                    *(const float4*)&cb[(k0 + r) * DIM + dt * DC + q * 4];
            }
            __syncthreads();
            #pragma unroll
            for (int dq = 0; dq < DC / 4; ++dq) {
                float4 av[8], bv[8];
                #pragma unroll
                for (int r = 0; r < 8; ++r)
                    av[r] = *(const float4*)&As[r * 16 + tr][dq * 4];
                #pragma unroll
                for (int c = 0; c < 8; ++c)
                    bv[c] = *(const float4*)&Bs[c * 16 + tc][dq * 4];
                #pragma unroll
                for (int r = 0; r < 8; ++r)
                    #pragma unroll
                    for (int c = 0; c < 8; ++c)
                        acc[r][c] += av[r].x * bv[c].x + av[r].y * bv[c].y +
                                     av[r].z * bv[c].z + av[r].w * bv[c].w;
            }
        }
        // fold this tile into running argmin (c ascending -> k ascending)
        #pragma unroll
        for (int c = 0; c < 8; ++c) {
            int   kg = k0 + c * 16 + tc;
            float cn = ccn[kg];
            #pragma unroll
            for (int r = 0; r < 8; ++r) {
                float s = fmaf(-2.0f, acc[r][c], cn);
                if (s < best[r]) { best[r] = s; bidx[r] = kg; }
            }
        }
    }

    __syncthreads();
    #pragma unroll
    for (int r = 0; r < 8; ++r) {
        redv[r * 16 + tr][tc] = best[r];
        redi[r * 16 + tr][tc] = bidx[r];
    }
    __syncthreads();
    if (t < BM) {
        float bv = redv[t][0];
        int   bi = redi[t][0];
        #pragma unroll
        for (int j = 1; j < 16; ++j) {
            float v = redv[t][j];
            int   i2 = redi[t][j];
            if (v < bv || (v == bv && i2 < bi)) { bv = v; bi = i2; }
        }
        pval[(m0 + t) * KSPLIT + split] = bv;
        pidx[(m0 + t) * KSPLIT + split] = bi;
    }
}

// ---------------------------------------------------------------------------
// Kernel 4: reduce split partials -> idx; resid -= cb[idx]; per-vector
// sum(resid^2) -> rsum; write code (as float) to d_out. One wave per vector.
// ---------------------------------------------------------------------------
__global__ __launch_bounds__(256) void update_kernel(
    const float* __restrict__ cb,      // this depth's codebook
    const float* __restrict__ pval,
    const int*   __restrict__ pidx,
    float* __restrict__ resid,
    float* __restrict__ rsum,          // [NVEC] for this depth
    float* __restrict__ codes_out,     // d_out codes region (floats)
    int depth) {
    int n    = blockIdx.x * 4 + (threadIdx.x >> 6);
    int lane = threadIdx.x & 63;

    float bv = pval[n * KSPLIT];
    int   bi = pidx[n * KSPLIT];
    #pragma unroll
    for (int s = 1; s < KSPLIT; ++s) {
        float v  = pval[n * KSPLIT + s];
        int   i2 = pidx[n * KSPLIT + s];
        if (v < bv || (v == bv && i2 < bi)) { bv = v; bi = i2; }
    }

    float4 q = *(const float4*)&cb[bi * DIM + lane * 4];
    float4 r = *(float4*)&resid[n * DIM + lane * 4];
    r.x -= q.x; r.y -= q.y; r.z -= q.z; r.w -= q.w;
    *(float4*)&resid[n * DIM + lane * 4] = r;

    float s2 = r.x * r.x + r.y * r.y + r.z * r.z + r.w * r.w;
    #pragma unroll
    for (int off = 32; off > 0; off >>= 1) s2 += __shfl_down(s2, off, 64);
    if (lane == 0) {
        rsum[n] = s2;
        codes_out[n * DEPTH + depth] = (float)bi;
    }
}

// ---------------------------------------------------------------------------
// Kernel 5: quants = x - resid (in place in d_out); block 0 also reduces the
// commitment loss deterministically.
// ---------------------------------------------------------------------------
__global__ __launch_bounds__(256) void finalize(const float* __restrict__ x,
                                                float* __restrict__ out,
                                                const float* __restrict__ rsum) {
    int i = blockIdx.x * blockDim.x + threadIdx.x;   // float4 index
    float4 r  = *(float4*)&out[i * 4];               // resid
    float4 xv = *(const float4*)&x[i * 4];
    float4 o;
    o.x = xv.x - r.x; o.y = xv.y - r.y; o.z = xv.z - r.z; o.w = xv.w - r.w;
    *(float4*)&out[i * 4] = o;

    if (blockIdx.x == 0) {
        __shared__ float sm[256];
        float s = 0.f;
        for (int j = threadIdx.x; j < DEPTH * NVEC; j += 256) s += rsum[j];
        sm[threadIdx.x] = s;
        __syncthreads();
        for (int off = 128; off > 0; off >>= 1) {
            if (threadIdx.x < off) sm[threadIdx.x] += sm[threadIdx.x + off];
            __syncthreads();
        }
        if (threadIdx.x == 0)
            out[NVEC * DIM] = sm[0] / (float)DEPTH / (float)(NVEC * DIM);
    }
}

// ---------------------------------------------------------------------------
extern "C" void kernel_launch(void* const* d_in, const int* in_sizes, int n_in,
                              void* d_out, int out_size, void* d_ws, size_t ws_size,
                              hipStream_t stream) {
    const float* x  = (const float*)d_in[0];   // [8,32,32,256]
    const float* cb = (const float*)d_in[1];   // [4,8192,256]
    float* out = (float*)d_out;
    float* ws  = (float*)d_ws;

    // ws layout (floats): cc[4*8192] | pval[8192*4] | pidx[8192*4] | rsum[4*8192]
    float* cc   = ws;
    float* pval = ws + 32768;
    int*   pidx = (int*)(ws + 65536);
    float* rsum = ws + 98304;

    float* resid     = out;                    // reuse quants region as resid
    float* codes_out = out + NVEC * DIM + 1;   // after loss scalar

    prep_cc<<<(DEPTH * NCODE) / 4, 256, 0, stream>>>(cb, cc);
    init_resid<<<(NVEC * DIM / 4) / 256, 256, 0, stream>>>(x, resid);

    for (int i = 0; i < DEPTH; ++i) {
        argmin_kernel<<<(NVEC / BM) * KSPLIT, 256, 0, stream>>>(
            resid, cb + (size_t)i * NCODE * DIM, cc + i * NCODE, pval, pidx);
        update_kernel<<<NVEC / 4, 256, 0, stream>>>(
            cb + (size_t)i * NCODE * DIM, pval, pidx, resid,
            rsum + i * NVEC, codes_out, i);
    }
    finalize<<<(NVEC * DIM / 4) / 256, 256, 0, stream>>>(x, out, rsum);
}

// Round 2
// 1038.656 us; speedup vs baseline: 7.7943x; 7.7943x over previous
//
#include <hip/hip_runtime.h>

#define DIM   256
#define NVEC  8192
#define NCODE 8192
#define DEPTH 4

#define KBLK  16                 // k-splits; 512 codes per coarse block
#define KC    (NCODE / KBLK)
#define TN    128                // codes per inner tile
#define FCAP  2048
#define FLAG_TAU 0.06f

typedef short  b8 __attribute__((ext_vector_type(8)));   // 8 bf16 raw
typedef short  b4 __attribute__((ext_vector_type(4)));
typedef float  f4 __attribute__((ext_vector_type(4)));

static __device__ __forceinline__ unsigned short f2bf(float f) {
  unsigned u = __float_as_uint(f);
  return (unsigned short)((u + 0x7FFFu + ((u >> 16) & 1u)) >> 16);  // RNE
}

static __device__ __forceinline__ void gll16(const void* g, void* l) {
  __builtin_amdgcn_global_load_lds(
      (const __attribute__((address_space(1))) void*)g,
      (__attribute__((address_space(3))) void*)l, 16, 0, 0);
}

// ---------------------------------------------------------------------------
// prep: codebook f32 -> bf16 + row norms. One wave per code row.
// ---------------------------------------------------------------------------
__global__ __launch_bounds__(256) void prep_cb(const float* __restrict__ cb_all,
                                               unsigned short* __restrict__ cbh,
                                               float* __restrict__ cc) {
  int row  = blockIdx.x * 4 + (threadIdx.x >> 6);
  int lane = threadIdx.x & 63;
  float4 v = *(const float4*)&cb_all[(size_t)row * DIM + lane * 4];
  unsigned short h0 = f2bf(v.x), h1 = f2bf(v.y), h2 = f2bf(v.z), h3 = f2bf(v.w);
  b4 hv; hv[0] = (short)h0; hv[1] = (short)h1; hv[2] = (short)h2; hv[3] = (short)h3;
  *(b4*)&cbh[(size_t)row * DIM + lane * 4] = hv;
  float s = v.x * v.x + v.y * v.y + v.z * v.z + v.w * v.w;
  #pragma unroll
  for (int off = 32; off > 0; off >>= 1) s += __shfl_down(s, off, 64);
  if (lane == 0) cc[row] = s;
}

// ---------------------------------------------------------------------------
// init: resid = x (f32, in d_out), rb = bf16(x), rsum0 = ||x||^2
// ---------------------------------------------------------------------------
__global__ __launch_bounds__(256) void init_kernel(const float* __restrict__ x,
                                                   float* __restrict__ resid,
                                                   unsigned short* __restrict__ rb,
                                                   float* __restrict__ rsum0) {
  int n    = blockIdx.x * 4 + (threadIdx.x >> 6);
  int lane = threadIdx.x & 63;
  float4 v = *(const float4*)&x[(size_t)n * DIM + lane * 4];
  *(float4*)&resid[(size_t)n * DIM + lane * 4] = v;
  b4 hv; hv[0] = (short)f2bf(v.x); hv[1] = (short)f2bf(v.y);
  hv[2] = (short)f2bf(v.z); hv[3] = (short)f2bf(v.w);
  *(b4*)&rb[(size_t)n * DIM + lane * 4] = hv;
  float s = v.x * v.x + v.y * v.y + v.z * v.z + v.w * v.w;
  #pragma unroll
  for (int off = 32; off > 0; off >>= 1) s += __shfl_down(s, off, 64);
  if (lane == 0) rsum0[n] = s;
}

// ---------------------------------------------------------------------------
// coarse: bf16 MFMA distance GEMM + per-row top-2 over 512 codes.
// grid = 64 mblk x 16 kblk. 4 waves as 2x2 (mw,kw); wave tile 64x64.
// LDS tiles [128 rows][64 dims] bf16 = 128B rows, XOR swizzle slot^=(row&7)
// applied on BOTH the global_load_lds source and the ds_read address.
// ---------------------------------------------------------------------------
__global__ __launch_bounds__(256, 2) void coarse_kernel(
    const unsigned short* __restrict__ rb,
    const unsigned short* __restrict__ cbh,   // this depth
    const float* __restrict__ cc,             // this depth
    float* __restrict__ pv1, int* __restrict__ pi1, float* __restrict__ pv2) {
  __shared__ __align__(16) char Ash[128 * 128];
  __shared__ __align__(16) char Bsh[128 * 128];

  const int tid = threadIdx.x;
  const int w   = tid >> 6;
  const int l   = tid & 63;
  const int mw  = w >> 1, kw = w & 1;
  const int mblk = blockIdx.x >> 4;
  const int kblk = blockIdx.x & 15;
  const int m0 = mblk * 128;
  const int K0 = kblk * KC;

  float rv1 = 3.4e38f, rv2 = 3.4e38f;   // running top2 (threads < 128)
  int   ri1 = 0;

  for (int kt = 0; kt < 4; ++kt) {
    f4 acc[4][4];
    #pragma unroll
    for (int i = 0; i < 4; ++i)
      #pragma unroll
      for (int j = 0; j < 4; ++j)
        acc[i][j] = (f4){0.f, 0.f, 0.f, 0.f};

    for (int dt = 0; dt < 4; ++dt) {
      __syncthreads();                       // LDS safe to overwrite
      #pragma unroll
      for (int it = 0; it < 4; ++it) {
        int o   = it * 256 + tid;            // 16B chunk id 0..1023
        int row = o >> 3;                    // 8 chunks per 128B row
        int ssl = (o & 7) ^ (row & 7);       // pre-swizzled source slot
        const char* sa = (const char*)rb +
            ((size_t)(m0 + row)) * 512 + dt * 128 + ssl * 16;
        const char* sb = (const char*)cbh +
            ((size_t)(K0 + kt * TN + row)) * 512 + dt * 128 + ssl * 16;
        gll16(sa, Ash + (it * 256 + w * 64) * 16);
        gll16(sb, Bsh + (it * 256 + w * 64) * 16);
      }
      __syncthreads();

      #pragma unroll
      for (int kk = 0; kk < 2; ++kk) {
        b8 af[4], bfr[4];
        #pragma unroll
        for (int mf = 0; mf < 4; ++mf) {
          int row = mw * 64 + mf * 16 + (l & 15);
          int sl  = (kk * 4 + (l >> 4)) ^ (row & 7);
          af[mf] = *(const b8*)(Ash + row * 128 + sl * 16);
        }
        #pragma unroll
        for (int nf = 0; nf < 4; ++nf) {
          int row = kw * 64 + nf * 16 + (l & 15);
          int sl  = (kk * 4 + (l >> 4)) ^ (row & 7);
          bfr[nf] = *(const b8*)(Bsh + row * 128 + sl * 16);
        }
        #pragma unroll
        for (int mf = 0; mf < 4; ++mf)
          #pragma unroll
          for (int nf = 0; nf < 4; ++nf)
            acc[mf][nf] = __builtin_amdgcn_mfma_f32_16x16x32_bf16(
                af[mf], bfr[nf], acc[mf][nf], 0, 0, 0);
      }
    }

    __syncthreads();   // all ds_reads of Bsh done -> can alias as merge buf
    float* Mv1 = (float*)Bsh;                // [128][2]
    int*   Mi1 = (int*)(Bsh + 1024);
    float* Mv2 = (float*)(Bsh + 2048);

    float cn[4];
    #pragma unroll
    for (int nf = 0; nf < 4; ++nf)
      cn[nf] = cc[K0 + kt * TN + kw * 64 + nf * 16 + (l & 15)];

    #pragma unroll
    for (int mf = 0; mf < 4; ++mf) {
      #pragma unroll
      for (int r = 0; r < 4; ++r) {
        float v1 = 3.4e38f, v2 = 3.4e38f; int i1 = -1;
        #pragma unroll
        for (int nf = 0; nf < 4; ++nf) {
          int   kg = K0 + kt * TN + kw * 64 + nf * 16 + (l & 15);
          float s  = fmaf(-2.f, acc[mf][nf][r], cn[nf]);
          if (s < v1 || (s == v1 && kg < i1)) { v2 = v1; v1 = s; i1 = kg; }
          else v2 = fminf(v2, s);
        }
        #pragma unroll
        for (int m = 1; m < 16; m <<= 1) {   // butterfly over l&15 group
          float qv1 = __shfl_xor(v1, m);
          int   qi1 = __shfl_xor(i1, m);
          float qv2 = __shfl_xor(v2, m);
          bool  qw  = (qv1 < v1) || (qv1 == v1 && qi1 < i1);
          float lose = qw ? v1 : qv1;
          float wv2  = qw ? qv2 : v2;
          v2 = fminf(wv2, lose);
          if (qw) { v1 = qv1; i1 = qi1; }
        }
        if ((l & 15) == 0) {
          int rowL = mw * 64 + mf * 16 + (l >> 4) * 4 + r;
          Mv1[rowL * 2 + kw] = v1; Mi1[rowL * 2 + kw] = i1; Mv2[rowL * 2 + kw] = v2;
        }
      }
    }
    __syncthreads();
    if (tid < 128) {
      float a1 = Mv1[tid * 2],     a2 = Mv2[tid * 2];     int a1i = Mi1[tid * 2];
      float b1 = Mv1[tid * 2 + 1], b2 = Mv2[tid * 2 + 1]; int b1i = Mi1[tid * 2 + 1];
      bool  bw = (b1 < a1) || (b1 == a1 && b1i < a1i);
      float v1 = bw ? b1 : a1; int i1 = bw ? b1i : a1i;
      float v2 = fminf(bw ? b2 : a2, bw ? a1 : b1);
      bool  nw = (v1 < rv1) || (v1 == rv1 && i1 < ri1);
      float lose = nw ? rv1 : v1;
      float wv2  = nw ? v2 : rv2;
      rv2 = fminf(wv2, lose);
      if (nw) { rv1 = v1; ri1 = i1; }
    }
  }
  if (tid < 128) {
    int n = m0 + tid;
    pv1[n * KBLK + kblk] = rv1;
    pi1[n * KBLK + kblk] = ri1;
    pv2[n * KBLK + kblk] = rv2;
  }
}

// ---------------------------------------------------------------------------
// merge: global top2 over KBLK partials; provisional idx; flag uncertain rows.
// ---------------------------------------------------------------------------
__global__ __launch_bounds__(256) void merge_kernel(
    const float* __restrict__ pv1, const int* __restrict__ pi1,
    const float* __restrict__ pv2, const float* __restrict__ vnorm,
    int* __restrict__ idx, int* __restrict__ flist, int* __restrict__ fcount) {
  int n = blockIdx.x * 256 + threadIdx.x;
  float v1 = 3.4e38f, v2 = 3.4e38f; int i1 = 0;
  for (int kb = 0; kb < KBLK; ++kb) {
    float b1 = pv1[n * KBLK + kb]; int b1i = pi1[n * KBLK + kb];
    float b2 = pv2[n * KBLK + kb];
    bool  bw = (b1 < v1) || (b1 == v1 && b1i < i1);
    float lose = bw ? v1 : b1;
    float wv2  = bw ? b2 : v2;
    v2 = fminf(wv2, lose);
    if (bw) { v1 = b1; i1 = b1i; }
  }
  idx[n] = i1;
  if (v2 - v1 < FLAG_TAU * sqrtf(vnorm[n])) {
    int s = atomicAdd(fcount, 1);
    if (s < FCAP) flist[s] = n;
  }
}

// ---------------------------------------------------------------------------
// fb_scan: exact f32 distances for flagged vectors, split over 8 k-slices.
// grid = 2048 (256 vec-chunks x 8 kb); 8 vectors per chunk.
// ---------------------------------------------------------------------------
__global__ __launch_bounds__(256) void fb_scan(
    const float* __restrict__ resid, const float* __restrict__ cb,
    const float* __restrict__ cc, const int* __restrict__ flist,
    const int* __restrict__ fcount,
    float* __restrict__ fpv, int* __restrict__ fpi) {
  __shared__ float vs[8][DIM];
  __shared__ float rv[8][256];
  __shared__ int   ri[8][256];
  int cnt = min(*fcount, FCAP);
  int kb  = blockIdx.x & 7;
  int t   = threadIdx.x;
  for (int g = blockIdx.x >> 3; g * 8 < cnt; g += 256) {
    int nv = min(8, cnt - g * 8);
    __syncthreads();
    for (int v = 0; v < 8; ++v)
      if (v < nv) vs[v][t] = resid[(size_t)flist[g * 8 + v] * DIM + t];
    __syncthreads();
    float best[8]; int bi[8];
    #pragma unroll
    for (int v = 0; v < 8; ++v) { best[v] = 3.4e38f; bi[v] = 0; }
    for (int c = 0; c < 4; ++c) {          // ascending k for tie semantics
      int k = kb * 1024 + c * 256 + t;
      float dot[8];
      #pragma unroll
      for (int v = 0; v < 8; ++v) dot[v] = 0.f;
      for (int d = 0; d < DIM; d += 4) {
        float4 cv = *(const float4*)&cb[(size_t)k * DIM + d];
        #pragma unroll
        for (int v = 0; v < 8; ++v)
          dot[v] = fmaf(cv.x, vs[v][d],
                   fmaf(cv.y, vs[v][d + 1],
                   fmaf(cv.z, vs[v][d + 2],
                   fmaf(cv.w, vs[v][d + 3], dot[v]))));
      }
      float cnv = cc[k];
      #pragma unroll
      for (int v = 0; v < 8; ++v) {
        float s = fmaf(-2.f, dot[v], cnv);
        if (s < best[v]) { best[v] = s; bi[v] = k; }
      }
    }
    #pragma unroll
    for (int v = 0; v < 8; ++v) { rv[v][t] = best[v]; ri[v][t] = bi[v]; }
    __syncthreads();
    for (int off = 128; off > 0; off >>= 1) {
      if (t < off) {
        #pragma unroll
        for (int v = 0; v < 8; ++v) {
          float b1 = rv[v][t + off]; int b1i = ri[v][t + off];
          if (b1 < rv[v][t] || (b1 == rv[v][t] && b1i < ri[v][t])) {
            rv[v][t] = b1; ri[v][t] = b1i;
          }
        }
      }
      __syncthreads();
    }
    if (t < nv) { fpv[(g * 8 + t) * 8 + kb] = rv[t][0]; fpi[(g * 8 + t) * 8 + kb] = ri[t][0]; }
  }
}

__global__ __launch_bounds__(256) void fb_merge(
    const float* __restrict__ fpv, const int* __restrict__ fpi,
    const int* __restrict__ flist, const int* __restrict__ fcount,
    int* __restrict__ idx) {
  int s = blockIdx.x * 256 + threadIdx.x;
  int cnt = min(*fcount, FCAP);
  if (s >= cnt) return;
  float v1 = 3.4e38f; int i1 = 0;
  for (int kb = 0; kb < 8; ++kb) {
    float b = fpv[s * 8 + kb]; int b1i = fpi[s * 8 + kb];
    if (b < v1 || (b == v1 && b1i < i1)) { v1 = b; i1 = b1i; }
  }
  idx[flist[s]] = i1;
}

// ---------------------------------------------------------------------------
// update: resid -= cb[idx]; rewrite rb; rsum (next-depth norm + loss term);
// write code as float. One wave per vector.
// ---------------------------------------------------------------------------
__global__ __launch_bounds__(256) void update_kernel(
    const float* __restrict__ cb, const int* __restrict__ idx,
    float* __restrict__ resid, unsigned short* __restrict__ rb,
    float* __restrict__ rsum_out, float* __restrict__ codes_out, int depth) {
  int n    = blockIdx.x * 4 + (threadIdx.x >> 6);
  int lane = threadIdx.x & 63;
  int bi   = idx[n];
  float4 q = *(const float4*)&cb[(size_t)bi * DIM + lane * 4];
  float4 r = *(float4*)&resid[(size_t)n * DIM + lane * 4];
  r.x -= q.x; r.y -= q.y; r.z -= q.z; r.w -= q.w;
  *(float4*)&resid[(size_t)n * DIM + lane * 4] = r;
  b4 hv; hv[0] = (short)f2bf(r.x); hv[1] = (short)f2bf(r.y);
  hv[2] = (short)f2bf(r.z); hv[3] = (short)f2bf(r.w);
  *(b4*)&rb[(size_t)n * DIM + lane * 4] = hv;
  float s2 = r.x * r.x + r.y * r.y + r.z * r.z + r.w * r.w;
  #pragma unroll
  for (int off = 32; off > 0; off >>= 1) s2 += __shfl_down(s2, off, 64);
  if (lane == 0) {
    rsum_out[n] = s2;
    codes_out[n * DEPTH + depth] = (float)bi;
  }
}

// ---------------------------------------------------------------------------
// finalize: quants = x - resid (in place); block 0 reduces commitment loss.
// ---------------------------------------------------------------------------
__global__ __launch_bounds__(256) void finalize(const float* __restrict__ x,
                                                float* __restrict__ out,
                                                const float* __restrict__ rsumL) {
  int i = blockIdx.x * blockDim.x + threadIdx.x;
  float4 r  = *(float4*)&out[(size_t)i * 4];
  float4 xv = *(const float4*)&x[(size_t)i * 4];
  float4 o;
  o.x = xv.x - r.x; o.y = xv.y - r.y; o.z = xv.z - r.z; o.w = xv.w - r.w;
  *(float4*)&out[(size_t)i * 4] = o;

  if (blockIdx.x == 0) {
    __shared__ float sm[256];
    float s = 0.f;
    for (int j = threadIdx.x; j < DEPTH * NVEC; j += 256) s += rsumL[j];
    sm[threadIdx.x] = s;
    __syncthreads();
    for (int off = 128; off > 0; off >>= 1) {
      if (threadIdx.x < off) sm[threadIdx.x] += sm[threadIdx.x + off];
      __syncthreads();
    }
    if (threadIdx.x == 0)
      out[NVEC * DIM] = sm[0] / (float)DEPTH / (float)(NVEC * DIM);
  }
}

// ---------------------------------------------------------------------------
extern "C" void kernel_launch(void* const* d_in, const int* in_sizes, int n_in,
                              void* d_out, int out_size, void* d_ws, size_t ws_size,
                              hipStream_t stream) {
  const float* x  = (const float*)d_in[0];
  const float* cb = (const float*)d_in[1];
  float* out = (float*)d_out;
  char*  wsb = (char*)d_ws;

  // ws layout (~22 MB; assumes ws_size >= 23 MB)
  unsigned short* cbh   = (unsigned short*)(wsb);               // 16 MB
  unsigned short* rb    = (unsigned short*)(wsb + 16777216);    // 4 MB
  float* cc    = (float*)(wsb + 20971520);                      // 128 KB
  float* pv1   = (float*)(wsb + 21102592);                      // 512 KB
  int*   pi1   = (int*)  (wsb + 21626880);                      // 512 KB
  float* pv2   = (float*)(wsb + 22151168);                      // 512 KB
  float* rsum  = (float*)(wsb + 22675456);                      // 5*8192 f32
  int*   idx   = (int*)  (wsb + 22839296);
  int*   flist = (int*)  (wsb + 22872064);
  int*   fcount= (int*)  (wsb + 22880256);
  float* fpv   = (float*)(wsb + 22880512);
  int*   fpi   = (int*)  (wsb + 22946048);

  float* resid     = out;                    // quants region doubles as resid
  float* codes_out = out + NVEC * DIM + 1;

  prep_cb<<<(DEPTH * NCODE) / 4, 256, 0, stream>>>(cb, cbh, cc);
  init_kernel<<<NVEC / 4, 256, 0, stream>>>(x, resid, rb, rsum);

  for (int d = 0; d < DEPTH; ++d) {
    const size_t cbo = (size_t)d * NCODE * DIM;
    coarse_kernel<<<(NVEC / 128) * KBLK, 256, 0, stream>>>(
        rb, cbh + cbo, cc + d * NCODE, pv1, pi1, pv2);
    hipMemsetAsync(fcount, 0, 4, stream);
    merge_kernel<<<NVEC / 256, 256, 0, stream>>>(
        pv1, pi1, pv2, rsum + d * NVEC, idx, flist, fcount);
    fb_scan<<<2048, 256, 0, stream>>>(
        resid, cb + cbo, cc + d * NCODE, flist, fcount, fpv, fpi);
    fb_merge<<<FCAP / 256, 256, 0, stream>>>(fpv, fpi, flist, fcount, idx);
    update_kernel<<<NVEC / 4, 256, 0, stream>>>(
        cb + cbo, idx, resid, rb, rsum + (d + 1) * NVEC, codes_out, d);
  }
  finalize<<<(NVEC * DIM / 4) / 256, 256, 0, stream>>>(x, out, rsum + NVEC);
}

// Round 4
// 953.127 us; speedup vs baseline: 8.4937x; 1.0897x over previous
//
#include <hip/hip_runtime.h>

#define DIM   256
#define NVEC  8192
#define NCODE 8192
#define DEPTH 4

#define KBLK  8                  // k-splits; 1024 codes per coarse block
#define KC    (NCODE / KBLK)
#define FCAP  8192               // = NVEC: flag list can never overflow
#define KAPPA 0.025f

typedef short  b8 __attribute__((ext_vector_type(8)));   // 8 bf16 raw
typedef short  b4 __attribute__((ext_vector_type(4)));
typedef float  f4 __attribute__((ext_vector_type(4)));

static __device__ __forceinline__ unsigned short f2bf(float f) {
  unsigned u = __float_as_uint(f);
  return (unsigned short)((u + 0x7FFFu + ((u >> 16) & 1u)) >> 16);  // RNE
}

static __device__ __forceinline__ void gll16(const void* g, void* l) {
  __builtin_amdgcn_global_load_lds(
      (const __attribute__((address_space(1))) void*)g,
      (__attribute__((address_space(3))) void*)l, 16, 0, 0);
}

// ---------------------------------------------------------------------------
// prep: codebook f32 -> bf16; true norms ||c||^2 (exact fb) and bf16-norms
// ||ĉ||^2 (coarse scores, consistent with bf16 dot). One wave per code row.
// ---------------------------------------------------------------------------
__global__ __launch_bounds__(256) void prep_cb(const float* __restrict__ cb_all,
                                               unsigned short* __restrict__ cbh,
                                               float* __restrict__ cc,
                                               float* __restrict__ cchat) {
  int row  = blockIdx.x * 4 + (threadIdx.x >> 6);
  int lane = threadIdx.x & 63;
  float4 v = *(const float4*)&cb_all[(size_t)row * DIM + lane * 4];
  b4 hv;
  float st = 0.f, sh = 0.f;
  float vv[4] = {v.x, v.y, v.z, v.w};
  #pragma unroll
  for (int j = 0; j < 4; ++j) {
    unsigned short h = f2bf(vv[j]);
    hv[j] = (short)h;
    float hf = __uint_as_float(((unsigned)h) << 16);
    st += vv[j] * vv[j];
    sh += hf * hf;
  }
  *(b4*)&cbh[(size_t)row * DIM + lane * 4] = hv;
  #pragma unroll
  for (int off = 32; off > 0; off >>= 1) {
    st += __shfl_down(st, off, 64);
    sh += __shfl_down(sh, off, 64);
  }
  if (lane == 0) { cc[row] = st; cchat[row] = sh; }
}

// ---------------------------------------------------------------------------
// init: resid = x (f32, in d_out), rb = bf16(x), rsum0 = ||x||^2
// ---------------------------------------------------------------------------
__global__ __launch_bounds__(256) void init_kernel(const float* __restrict__ x,
                                                   float* __restrict__ resid,
                                                   unsigned short* __restrict__ rb,
                                                   float* __restrict__ rsum0) {
  int n    = blockIdx.x * 4 + (threadIdx.x >> 6);
  int lane = threadIdx.x & 63;
  float4 v = *(const float4*)&x[(size_t)n * DIM + lane * 4];
  *(float4*)&resid[(size_t)n * DIM + lane * 4] = v;
  b4 hv; hv[0] = (short)f2bf(v.x); hv[1] = (short)f2bf(v.y);
  hv[2] = (short)f2bf(v.z); hv[3] = (short)f2bf(v.w);
  *(b4*)&rb[(size_t)n * DIM + lane * 4] = hv;
  float s = v.x * v.x + v.y * v.y + v.z * v.z + v.w * v.w;
  #pragma unroll
  for (int off = 32; off > 0; off >>= 1) s += __shfl_down(s, off, 64);
  if (lane == 0) rsum0[n] = s;
}

// ---------------------------------------------------------------------------
// coarse: bf16 MFMA distance GEMM + per-thread register top-2 across tiles.
// score ŝ[n][k] = ||ĉ_k||^2 - 2<v̂_n, ĉ_k>
// grid = 64 mblk x 8 kblk (512 = 2/CU). 4 waves as 2x2; wave tile 64x64.
// A,B: gll16 with pre-swizzled global source, linear LDS dest (R2-proven).
// ---------------------------------------------------------------------------
__global__ __launch_bounds__(256, 2) void coarse_kernel(
    const unsigned short* __restrict__ rb,
    const unsigned short* __restrict__ cbh,   // this depth
    const float* __restrict__ cchat,          // this depth, ||ĉ||^2
    float* __restrict__ pv1, int* __restrict__ pi1, float* __restrict__ pv2) {
  __shared__ __align__(16) char Ash[128 * 128];  // 128 rows x 64 bf16
  __shared__ __align__(16) char Bsh[128 * 128];  // 128 codes x 64 bf16

  const int tid  = threadIdx.x;
  const int w    = tid >> 6;
  const int l    = tid & 63;
  const int mw   = w >> 1, kw = w & 1;
  const int mblk = blockIdx.x >> 3;
  const int kblk = blockIdx.x & 7;
  const int m0   = mblk * 128;
  const int K0   = kblk * KC;

  float tv1[16], tv2[16];
  int   ti1[16];
  #pragma unroll
  for (int s = 0; s < 16; ++s) { tv1[s] = 3.4e38f; tv2[s] = 3.4e38f; ti1[s] = 0; }

  for (int kt = 0; kt < 8; ++kt) {
    f4 acc[4][4];
    #pragma unroll
    for (int i = 0; i < 4; ++i)
      #pragma unroll
      for (int j = 0; j < 4; ++j)
        acc[i][j] = (f4){0.f, 0.f, 0.f, 0.f};

    for (int dt = 0; dt < 4; ++dt) {
      __syncthreads();                          // previous reads done
      #pragma unroll
      for (int it = 0; it < 4; ++it) {          // 1024 chunks each: full tile
        int o   = it * 256 + tid;               // 16B chunk id 0..1023
        int row = o >> 3;                       // rows 0..127
        int ssl = (o & 7) ^ (row & 7);          // pre-swizzled source slot
        const char* sa = (const char*)rb +
            ((size_t)(m0 + row) * DIM + dt * 64 + ssl * 8) * 2;
        const char* sb = (const char*)cbh +
            ((size_t)(K0 + kt * 128 + row) * DIM + dt * 64 + ssl * 8) * 2;
        gll16(sa, Ash + (it * 256 + w * 64) * 16);
        gll16(sb, Bsh + (it * 256 + w * 64) * 16);
      }
      __syncthreads();

      #pragma unroll
      for (int kk = 0; kk < 2; ++kk) {
        b8 af[4], bb[4];
        #pragma unroll
        for (int mf = 0; mf < 4; ++mf) {
          int row = mw * 64 + mf * 16 + (l & 15);
          int sl  = (kk * 4 + (l >> 4)) ^ (row & 7);
          af[mf] = *(const b8*)(Ash + row * 128 + sl * 16);
        }
        #pragma unroll
        for (int nf = 0; nf < 4; ++nf) {
          int row = kw * 64 + nf * 16 + (l & 15);
          int sl  = (kk * 4 + (l >> 4)) ^ (row & 7);
          bb[nf] = *(const b8*)(Bsh + row * 128 + sl * 16);
        }
        #pragma unroll
        for (int mf = 0; mf < 4; ++mf)
          #pragma unroll
          for (int nf = 0; nf < 4; ++nf)
            acc[mf][nf] = __builtin_amdgcn_mfma_f32_16x16x32_bf16(
                af[mf], bb[nf], acc[mf][nf], 0, 0, 0);
      }
    }

    // ---- fold tile into per-thread running top-2 (registers, static idx) ----
    float cn[4];
    #pragma unroll
    for (int nf = 0; nf < 4; ++nf)
      cn[nf] = cchat[K0 + kt * 128 + kw * 64 + nf * 16 + (l & 15)];
    #pragma unroll
    for (int mf = 0; mf < 4; ++mf)
      #pragma unroll
      for (int r = 0; r < 4; ++r) {
        const int s0 = mf * 4 + r;
        #pragma unroll
        for (int nf = 0; nf < 4; ++nf) {
          int   kg = K0 + kt * 128 + kw * 64 + nf * 16 + (l & 15);
          float s  = fmaf(-2.f, acc[mf][nf][r], cn[nf]);
          if (s < tv1[s0]) { tv2[s0] = tv1[s0]; tv1[s0] = s; ti1[s0] = kg; }
          else tv2[s0] = fminf(tv2[s0], s);
        }
      }
  }

  // ---- single end-of-block reduction ----
  __syncthreads();                 // all Bsh reads done -> alias as merge buf
  float* Mv1 = (float*)Bsh;        // [128][2]
  int*   Mi1 = (int*)(Bsh + 1024);
  float* Mv2 = (float*)(Bsh + 2048);

  #pragma unroll
  for (int s0 = 0; s0 < 16; ++s0) {
    float v1 = tv1[s0], v2 = tv2[s0];
    int   i1 = ti1[s0];
    #pragma unroll
    for (int m = 1; m < 16; m <<= 1) {     // butterfly over l&15 group
      float qv1 = __shfl_xor(v1, m);
      int   qi1 = __shfl_xor(i1, m);
      float qv2 = __shfl_xor(v2, m);
      bool  qw  = (qv1 < v1) || (qv1 == v1 && qi1 < i1);
      float lose = qw ? v1 : qv1;
      float wv2  = qw ? qv2 : v2;
      v2 = fminf(wv2, lose);
      if (qw) { v1 = qv1; i1 = qi1; }
    }
    if ((l & 15) == 0) {
      int mf = s0 >> 2, r = s0 & 3;
      int rowL = mw * 64 + mf * 16 + (l >> 4) * 4 + r;
      Mv1[rowL * 2 + kw] = v1; Mi1[rowL * 2 + kw] = i1; Mv2[rowL * 2 + kw] = v2;
    }
  }
  __syncthreads();
  if (tid < 128) {
    float a1 = Mv1[tid * 2],     a2 = Mv2[tid * 2];     int a1i = Mi1[tid * 2];
    float b1 = Mv1[tid * 2 + 1], b2 = Mv2[tid * 2 + 1]; int b1i = Mi1[tid * 2 + 1];
    bool  bw = (b1 < a1) || (b1 == a1 && b1i < a1i);
    float v1 = bw ? b1 : a1; int i1 = bw ? b1i : a1i;
    float v2 = fminf(bw ? b2 : a2, bw ? a1 : b1);
    int n = m0 + tid;
    pv1[n * KBLK + kblk] = v1;
    pi1[n * KBLK + kblk] = i1;
    pv2[n * KBLK + kblk] = v2;
  }
}

// ---------------------------------------------------------------------------
// merge: global top2 over KBLK partials; provisional idx; flag near-ties.
// margin: v2-v1 < KAPPA * ||v-ĉ||  (= sqrt(v1 + ||v||^2))
// ---------------------------------------------------------------------------
__global__ __launch_bounds__(256) void merge_kernel(
    const float* __restrict__ pv1, const int* __restrict__ pi1,
    const float* __restrict__ pv2, const float* __restrict__ vnorm,
    int* __restrict__ idx, int* __restrict__ flist, int* __restrict__ fcount) {
  int n = blockIdx.x * 256 + threadIdx.x;
  float v1 = 3.4e38f, v2 = 3.4e38f; int i1 = 0;
  #pragma unroll
  for (int kb = 0; kb < KBLK; ++kb) {
    float b1 = pv1[n * KBLK + kb]; int b1i = pi1[n * KBLK + kb];
    float b2 = pv2[n * KBLK + kb];
    bool  bw = (b1 < v1) || (b1 == v1 && b1i < i1);
    float lose = bw ? v1 : b1;
    float wv2  = bw ? b2 : v2;
    v2 = fminf(wv2, lose);
    if (bw) { v1 = b1; i1 = b1i; }
  }
  idx[n] = i1;
  float thr = KAPPA * sqrtf(fmaxf(v1 + vnorm[n], 0.f)) + 1e-5f;
  if (v2 - v1 < thr) {
    int s = atomicAdd(fcount, 1);
    flist[s] = n;                      // s < NVEC == FCAP always
  }
}

// ---------------------------------------------------------------------------
// fb_scan: exact f32 distances for flagged vectors, 8 k-slices. Register-
// blocked: dot[4 codes][8 vec] accumulators, float4 LDS reads (broadcast).
// ---------------------------------------------------------------------------
__global__ __launch_bounds__(256) void fb_scan(
    const float* __restrict__ resid, const float* __restrict__ cb,
    const float* __restrict__ cc, const int* __restrict__ flist,
    const int* __restrict__ fcount,
    float* __restrict__ fpv, int* __restrict__ fpi) {
  __shared__ float vs[8][DIM];
  __shared__ float rv[8][256];
  __shared__ int   ri[8][256];
  int cnt = min(*fcount, FCAP);
  int kb  = blockIdx.x & 7;
  int t   = threadIdx.x;
  for (int g = blockIdx.x >> 3; g * 8 < cnt; g += 256) {
    int nv = min(8, cnt - g * 8);
    __syncthreads();
    for (int v = 0; v < 8; ++v)
      if (v < nv) vs[v][t] = resid[(size_t)flist[g * 8 + v] * DIM + t];
    __syncthreads();

    float dot[4][8];
    #pragma unroll
    for (int c = 0; c < 4; ++c)
      #pragma unroll
      for (int v = 0; v < 8; ++v) dot[c][v] = 0.f;

    for (int d = 0; d < DIM; d += 4) {
      f4 vc[8];
      #pragma unroll
      for (int v = 0; v < 8; ++v) vc[v] = *(const f4*)&vs[v][d];
      #pragma unroll
      for (int c = 0; c < 4; ++c) {
        int k = kb * 1024 + c * 256 + t;
        f4 cv = *(const f4*)&cb[(size_t)k * DIM + d];
        #pragma unroll
        for (int v = 0; v < 8; ++v)
          dot[c][v] = fmaf(cv[0], vc[v][0],
                      fmaf(cv[1], vc[v][1],
                      fmaf(cv[2], vc[v][2],
                      fmaf(cv[3], vc[v][3], dot[c][v]))));
      }
    }

    float best[8]; int bi[8];
    #pragma unroll
    for (int v = 0; v < 8; ++v) { best[v] = 3.4e38f; bi[v] = 0; }
    #pragma unroll
    for (int c = 0; c < 4; ++c) {         // ascending k within thread
      int k = kb * 1024 + c * 256 + t;
      float cnv = cc[k];
      #pragma unroll
      for (int v = 0; v < 8; ++v) {
        float s = fmaf(-2.f, dot[c][v], cnv);
        if (s < best[v]) { best[v] = s; bi[v] = k; }
      }
    }
    #pragma unroll
    for (int v = 0; v < 8; ++v) { rv[v][t] = best[v]; ri[v][t] = bi[v]; }
    __syncthreads();
    for (int off = 128; off > 0; off >>= 1) {
      if (t < off) {
        #pragma unroll
        for (int v = 0; v < 8; ++v) {
          float b1 = rv[v][t + off]; int b1i = ri[v][t + off];
          if (b1 < rv[v][t] || (b1 == rv[v][t] && b1i < ri[v][t])) {
            rv[v][t] = b1; ri[v][t] = b1i;
          }
        }
      }
      __syncthreads();
    }
    if (t < nv) { fpv[(g * 8 + t) * 8 + kb] = rv[t][0]; fpi[(g * 8 + t) * 8 + kb] = ri[t][0]; }
  }
}

__global__ __launch_bounds__(256) void fb_merge(
    const float* __restrict__ fpv, const int* __restrict__ fpi,
    const int* __restrict__ flist, const int* __restrict__ fcount,
    int* __restrict__ idx) {
  int s = blockIdx.x * 256 + threadIdx.x;
  int cnt = min(*fcount, FCAP);
  if (s >= cnt) return;
  float v1 = 3.4e38f; int i1 = 0;
  #pragma unroll
  for (int kb = 0; kb < 8; ++kb) {
    float b = fpv[s * 8 + kb]; int b1i = fpi[s * 8 + kb];
    if (b < v1 || (b == v1 && b1i < i1)) { v1 = b; i1 = b1i; }
  }
  idx[flist[s]] = i1;
}

// ---------------------------------------------------------------------------
// update: resid -= cb[idx]; rb = bf16(resid); rsum (next norm = loss term);
// code out as float. One wave per vector.
// ---------------------------------------------------------------------------
__global__ __launch_bounds__(256) void update_kernel(
    const float* __restrict__ cb, const int* __restrict__ idx,
    float* __restrict__ resid, unsigned short* __restrict__ rb,
    float* __restrict__ rsum_out, float* __restrict__ codes_out, int depth) {
  int n    = blockIdx.x * 4 + (threadIdx.x >> 6);
  int lane = threadIdx.x & 63;
  int bi   = idx[n];
  float4 q = *(const float4*)&cb[(size_t)bi * DIM + lane * 4];
  float4 r = *(float4*)&resid[(size_t)n * DIM + lane * 4];
  r.x -= q.x; r.y -= q.y; r.z -= q.z; r.w -= q.w;
  *(float4*)&resid[(size_t)n * DIM + lane * 4] = r;
  b4 hv; hv[0] = (short)f2bf(r.x); hv[1] = (short)f2bf(r.y);
  hv[2] = (short)f2bf(r.z); hv[3] = (short)f2bf(r.w);
  *(b4*)&rb[(size_t)n * DIM + lane * 4] = hv;
  float s2 = r.x * r.x + r.y * r.y + r.z * r.z + r.w * r.w;
  #pragma unroll
  for (int off = 32; off > 0; off >>= 1) s2 += __shfl_down(s2, off, 64);
  if (lane == 0) {
    rsum_out[n] = s2;
    codes_out[n * DEPTH + depth] = (float)bi;
  }
}

// ---------------------------------------------------------------------------
// finalize: quants = x - resid (in place); block 0 reduces commitment loss.
// ---------------------------------------------------------------------------
__global__ __launch_bounds__(256) void finalize(const float* __restrict__ x,
                                                float* __restrict__ out,
                                                const float* __restrict__ rsumL) {
  int i = blockIdx.x * blockDim.x + threadIdx.x;
  float4 r  = *(float4*)&out[(size_t)i * 4];
  float4 xv = *(const float4*)&x[(size_t)i * 4];
  float4 o;
  o.x = xv.x - r.x; o.y = xv.y - r.y; o.z = xv.z - r.z; o.w = xv.w - r.w;
  *(float4*)&out[(size_t)i * 4] = o;

  if (blockIdx.x == 0) {
    __shared__ float sm[256];
    float s = 0.f;
    for (int j = threadIdx.x; j < DEPTH * NVEC; j += 256) s += rsumL[j];
    sm[threadIdx.x] = s;
    __syncthreads();
    for (int off = 128; off > 0; off >>= 1) {
      if (threadIdx.x < off) sm[threadIdx.x] += sm[threadIdx.x + off];
      __syncthreads();
    }
    if (threadIdx.x == 0)
      out[NVEC * DIM] = sm[0] / (float)DEPTH / (float)(NVEC * DIM);
  }
}

// ---------------------------------------------------------------------------
extern "C" void kernel_launch(void* const* d_in, const int* in_sizes, int n_in,
                              void* d_out, int out_size, void* d_ws, size_t ws_size,
                              hipStream_t stream) {
  const float* x  = (const float*)d_in[0];
  const float* cb = (const float*)d_in[1];
  float* out = (float*)d_out;
  char*  wsb = (char*)d_ws;

  // ws layout (~22.3 MB)
  unsigned short* cbh = (unsigned short*)(wsb);                 // 16 MB
  unsigned short* rb  = (unsigned short*)(wsb + 16777216);      // 4 MB
  float* cc    = (float*)(wsb + 20971520);                      // 128 KB
  float* cchat = (float*)(wsb + 21102592);                      // 128 KB
  float* pv1   = (float*)(wsb + 21233664);                      // 256 KB
  int*   pi1   = (int*)  (wsb + 21495808);                      // 256 KB
  float* pv2   = (float*)(wsb + 21757952);                      // 256 KB
  float* rsum  = (float*)(wsb + 22020096);                      // 160 KB
  int*   idx   = (int*)  (wsb + 22183936);                      // 32 KB
  int*   flist = (int*)  (wsb + 22216704);                      // 32 KB
  int*   fcount= (int*)  (wsb + 22249472);                      // 256 B
  // fpv/fpi alias pv1/pi1: dead after merge_kernel, reused by fb for 8192x8
  float* fpv   = pv1;
  int*   fpi   = pi1;

  float* resid     = out;                    // quants region doubles as resid
  float* codes_out = out + NVEC * DIM + 1;

  prep_cb<<<(DEPTH * NCODE) / 4, 256, 0, stream>>>(cb, cbh, cc, cchat);
  init_kernel<<<NVEC / 4, 256, 0, stream>>>(x, resid, rb, rsum);

  for (int d = 0; d < DEPTH; ++d) {
    const size_t cbo = (size_t)d * NCODE * DIM;
    coarse_kernel<<<(NVEC / 128) * KBLK, 256, 0, stream>>>(
        rb, cbh + cbo, cchat + d * NCODE, pv1, pi1, pv2);
    hipMemsetAsync(fcount, 0, 4, stream);
    merge_kernel<<<NVEC / 256, 256, 0, stream>>>(
        pv1, pi1, pv2, rsum + d * NVEC, idx, flist, fcount);
    fb_scan<<<2048, 256, 0, stream>>>(
        resid, cb + cbo, cc + d * NCODE, flist, fcount, fpv, fpi);
    fb_merge<<<FCAP / 256, 256, 0, stream>>>(fpv, fpi, flist, fcount, idx);
    update_kernel<<<NVEC / 4, 256, 0, stream>>>(
        cb + cbo, idx, resid, rb, rsum + (d + 1) * NVEC, codes_out, d);
  }
  finalize<<<(NVEC * DIM / 4) / 256, 256, 0, stream>>>(x, out, rsum + NVEC);
}

// Round 5
// 789.121 us; speedup vs baseline: 10.2590x; 1.2078x over previous
//
#include <hip/hip_runtime.h>

#define DIM   256
#define NVEC  8192
#define NCODE 8192
#define DEPTH 4

#define KBLK  16                 // coarse k-splits; 512 codes per block
#define KC    (NCODE / KBLK)
#define FCAP  8192               // = NVEC: flag list can never overflow
#define FKS   32                 // fallback k-slices (256 codes each)
#define KAPPA 0.025f

typedef short  b8 __attribute__((ext_vector_type(8)));   // 8 bf16 raw
typedef short  b4 __attribute__((ext_vector_type(4)));
typedef float  f4 __attribute__((ext_vector_type(4)));

static __device__ __forceinline__ unsigned short f2bf(float f) {
  unsigned u = __float_as_uint(f);
  return (unsigned short)((u + 0x7FFFu + ((u >> 16) & 1u)) >> 16);  // RNE
}

static __device__ __forceinline__ void gll16(const void* g, void* l) {
  __builtin_amdgcn_global_load_lds(
      (const __attribute__((address_space(1))) void*)g,
      (__attribute__((address_space(3))) void*)l, 16, 0, 0);
}

// ---------------------------------------------------------------------------
// prep_norms: all-depth row norms: true ||c||^2 (exact fb) and bf16 ||ĉ||^2
// (coarse scores). One wave per code row.
// ---------------------------------------------------------------------------
__global__ __launch_bounds__(256) void prep_norms(const float* __restrict__ cb_all,
                                                  float* __restrict__ cc,
                                                  float* __restrict__ cchat) {
  int row  = blockIdx.x * 4 + (threadIdx.x >> 6);
  int lane = threadIdx.x & 63;
  float4 v = *(const float4*)&cb_all[(size_t)row * DIM + lane * 4];
  float st = 0.f, sh = 0.f;
  float vv[4] = {v.x, v.y, v.z, v.w};
  #pragma unroll
  for (int j = 0; j < 4; ++j) {
    float hf = __uint_as_float(((unsigned)f2bf(vv[j])) << 16);
    st += vv[j] * vv[j];
    sh += hf * hf;
  }
  #pragma unroll
  for (int off = 32; off > 0; off >>= 1) {
    st += __shfl_down(st, off, 64);
    sh += __shfl_down(sh, off, 64);
  }
  if (lane == 0) { cc[row] = st; cchat[row] = sh; }
}

// ---------------------------------------------------------------------------
// prep_depth: this depth's codebook -> bf16 row-major (cbh) + f32 transposed
// (cbT[d][k]) via LDS 64x64 tile. grid = 128 kblocks x 4 dblocks.
// ---------------------------------------------------------------------------
__global__ __launch_bounds__(256) void prep_depth(const float* __restrict__ cbd,
                                                  unsigned short* __restrict__ cbh,
                                                  float* __restrict__ cbT) {
  __shared__ float ts[64][68];             // [d_local][k_local], pad 68
  const int kb = blockIdx.x >> 2, db = blockIdx.x & 3;
  const int k0 = kb * 64, d0 = db * 64;
  const int t  = threadIdx.x;
  const int r  = t >> 2;                   // code row 0..63
  const int c4 = (t & 3) * 16;             // dim offset (16 f32 per thread)

  const float* src = cbd + (size_t)(k0 + r) * DIM + d0 + c4;
  float4 q[4];
  #pragma unroll
  for (int i = 0; i < 4; ++i) q[i] = *(const float4*)(src + i * 4);

  // bf16 row-major write (16 values = 2x b8, 32B contiguous per thread)
  b8 h0, h1;
  #pragma unroll
  for (int j = 0; j < 4; ++j) { h0[j] = (short)f2bf(q[0][j]); h0[4 + j] = (short)f2bf(q[1][j]); }
  #pragma unroll
  for (int j = 0; j < 4; ++j) { h1[j] = (short)f2bf(q[2][j]); h1[4 + j] = (short)f2bf(q[3][j]); }
  *(b8*)&cbh[(size_t)(k0 + r) * DIM + d0 + c4]     = h0;
  *(b8*)&cbh[(size_t)(k0 + r) * DIM + d0 + c4 + 8] = h1;

  // LDS transpose
  #pragma unroll
  for (int i = 0; i < 4; ++i)
    #pragma unroll
    for (int j = 0; j < 4; ++j)
      ts[c4 + i * 4 + j][r] = q[i][j];
  __syncthreads();

  // write cbT: thread t -> d-row (t>>2), k-offset (t&3)*16
  const int dd = t >> 2, kk4 = (t & 3) * 16;
  float* dst = cbT + (size_t)(d0 + dd) * NCODE + k0 + kk4;
  #pragma unroll
  for (int q4 = 0; q4 < 4; ++q4)
    *(float4*)(dst + q4 * 4) = *(const float4*)&ts[dd][kk4 + q4 * 4];
}

// ---------------------------------------------------------------------------
// init: resid = x (f32, in d_out), rb = bf16(x), rsum0 = ||x||^2
// ---------------------------------------------------------------------------
__global__ __launch_bounds__(256) void init_kernel(const float* __restrict__ x,
                                                   float* __restrict__ resid,
                                                   unsigned short* __restrict__ rb,
                                                   float* __restrict__ rsum0) {
  int n    = blockIdx.x * 4 + (threadIdx.x >> 6);
  int lane = threadIdx.x & 63;
  float4 v = *(const float4*)&x[(size_t)n * DIM + lane * 4];
  *(float4*)&resid[(size_t)n * DIM + lane * 4] = v;
  b4 hv; hv[0] = (short)f2bf(v.x); hv[1] = (short)f2bf(v.y);
  hv[2] = (short)f2bf(v.z); hv[3] = (short)f2bf(v.w);
  *(b4*)&rb[(size_t)n * DIM + lane * 4] = hv;
  float s = v.x * v.x + v.y * v.y + v.z * v.z + v.w * v.w;
  #pragma unroll
  for (int off = 32; off > 0; off >>= 1) s += __shfl_down(s, off, 64);
  if (lane == 0) rsum0[n] = s;
}

// ---------------------------------------------------------------------------
// coarse: bf16 MFMA distance GEMM + per-thread register top-2 across tiles.
// grid = 64 mblk x KBLK kblk (1024 = 4/CU). 4 waves as 2x2; wave tile 64x64.
// A,B: gll16 with pre-swizzled global source, linear LDS dest.
// ---------------------------------------------------------------------------
__global__ __launch_bounds__(256, 2) void coarse_kernel(
    const unsigned short* __restrict__ rb,
    const unsigned short* __restrict__ cbh,   // this depth
    const float* __restrict__ cchat,          // this depth, ||ĉ||^2
    float* __restrict__ pv1, int* __restrict__ pi1, float* __restrict__ pv2) {
  __shared__ __align__(16) char Ash[128 * 128];  // 128 rows x 64 bf16
  __shared__ __align__(16) char Bsh[128 * 128];  // 128 codes x 64 bf16

  const int tid  = threadIdx.x;
  const int w    = tid >> 6;
  const int l    = tid & 63;
  const int mw   = w >> 1, kw = w & 1;
  const int mblk = blockIdx.x / KBLK;
  const int kblk = blockIdx.x % KBLK;
  const int m0   = mblk * 128;
  const int K0   = kblk * KC;

  float tv1[16], tv2[16];
  int   ti1[16];
  #pragma unroll
  for (int s = 0; s < 16; ++s) { tv1[s] = 3.4e38f; tv2[s] = 3.4e38f; ti1[s] = 0; }

  for (int kt = 0; kt < KC / 128; ++kt) {
    f4 acc[4][4];
    #pragma unroll
    for (int i = 0; i < 4; ++i)
      #pragma unroll
      for (int j = 0; j < 4; ++j)
        acc[i][j] = (f4){0.f, 0.f, 0.f, 0.f};

    for (int dt = 0; dt < 4; ++dt) {
      __syncthreads();                          // previous reads done
      #pragma unroll
      for (int it = 0; it < 4; ++it) {          // 1024 chunks each: full tile
        int o   = it * 256 + tid;               // 16B chunk id 0..1023
        int row = o >> 3;                       // rows 0..127
        int ssl = (o & 7) ^ (row & 7);          // pre-swizzled source slot
        const char* sa = (const char*)rb +
            ((size_t)(m0 + row) * DIM + dt * 64 + ssl * 8) * 2;
        const char* sb = (const char*)cbh +
            ((size_t)(K0 + kt * 128 + row) * DIM + dt * 64 + ssl * 8) * 2;
        gll16(sa, Ash + (it * 256 + w * 64) * 16);
        gll16(sb, Bsh + (it * 256 + w * 64) * 16);
      }
      __syncthreads();

      #pragma unroll
      for (int kk = 0; kk < 2; ++kk) {
        b8 af[4], bb[4];
        #pragma unroll
        for (int mf = 0; mf < 4; ++mf) {
          int row = mw * 64 + mf * 16 + (l & 15);
          int sl  = (kk * 4 + (l >> 4)) ^ (row & 7);
          af[mf] = *(const b8*)(Ash + row * 128 + sl * 16);
        }
        #pragma unroll
        for (int nf = 0; nf < 4; ++nf) {
          int row = kw * 64 + nf * 16 + (l & 15);
          int sl  = (kk * 4 + (l >> 4)) ^ (row & 7);
          bb[nf] = *(const b8*)(Bsh + row * 128 + sl * 16);
        }
        #pragma unroll
        for (int mf = 0; mf < 4; ++mf)
          #pragma unroll
          for (int nf = 0; nf < 4; ++nf)
            acc[mf][nf] = __builtin_amdgcn_mfma_f32_16x16x32_bf16(
                af[mf], bb[nf], acc[mf][nf], 0, 0, 0);
      }
    }

    // ---- fold tile into per-thread running top-2 (registers, static idx) ----
    float cn[4];
    #pragma unroll
    for (int nf = 0; nf < 4; ++nf)
      cn[nf] = cchat[K0 + kt * 128 + kw * 64 + nf * 16 + (l & 15)];
    #pragma unroll
    for (int mf = 0; mf < 4; ++mf)
      #pragma unroll
      for (int r = 0; r < 4; ++r) {
        const int s0 = mf * 4 + r;
        #pragma unroll
        for (int nf = 0; nf < 4; ++nf) {
          int   kg = K0 + kt * 128 + kw * 64 + nf * 16 + (l & 15);
          float s  = fmaf(-2.f, acc[mf][nf][r], cn[nf]);
          if (s < tv1[s0]) { tv2[s0] = tv1[s0]; tv1[s0] = s; ti1[s0] = kg; }
          else tv2[s0] = fminf(tv2[s0], s);
        }
      }
  }

  // ---- single end-of-block reduction ----
  __syncthreads();                 // all Bsh reads done -> alias as merge buf
  float* Mv1 = (float*)Bsh;        // [128][2]
  int*   Mi1 = (int*)(Bsh + 1024);
  float* Mv2 = (float*)(Bsh + 2048);

  #pragma unroll
  for (int s0 = 0; s0 < 16; ++s0) {
    float v1 = tv1[s0], v2 = tv2[s0];
    int   i1 = ti1[s0];
    #pragma unroll
    for (int m = 1; m < 16; m <<= 1) {     // butterfly over l&15 group
      float qv1 = __shfl_xor(v1, m);
      int   qi1 = __shfl_xor(i1, m);
      float qv2 = __shfl_xor(v2, m);
      bool  qw  = (qv1 < v1) || (qv1 == v1 && qi1 < i1);
      float lose = qw ? v1 : qv1;
      float wv2  = qw ? qv2 : v2;
      v2 = fminf(wv2, lose);
      if (qw) { v1 = qv1; i1 = qi1; }
    }
    if ((l & 15) == 0) {
      int mf = s0 >> 2, r = s0 & 3;
      int rowL = mw * 64 + mf * 16 + (l >> 4) * 4 + r;
      Mv1[rowL * 2 + kw] = v1; Mi1[rowL * 2 + kw] = i1; Mv2[rowL * 2 + kw] = v2;
    }
  }
  __syncthreads();
  if (tid < 128) {
    float a1 = Mv1[tid * 2],     a2 = Mv2[tid * 2];     int a1i = Mi1[tid * 2];
    float b1 = Mv1[tid * 2 + 1], b2 = Mv2[tid * 2 + 1]; int b1i = Mi1[tid * 2 + 1];
    bool  bw = (b1 < a1) || (b1 == a1 && b1i < a1i);
    float v1 = bw ? b1 : a1; int i1 = bw ? b1i : a1i;
    float v2 = fminf(bw ? b2 : a2, bw ? a1 : b1);
    int n = m0 + tid;
    pv1[n * KBLK + kblk] = v1;
    pi1[n * KBLK + kblk] = i1;
    pv2[n * KBLK + kblk] = v2;
  }
}

// ---------------------------------------------------------------------------
// merge: global top2 over KBLK partials; provisional idx; flag near-ties.
// ---------------------------------------------------------------------------
__global__ __launch_bounds__(256) void merge_kernel(
    const float* __restrict__ pv1, const int* __restrict__ pi1,
    const float* __restrict__ pv2, const float* __restrict__ vnorm,
    int* __restrict__ idx, int* __restrict__ flist, int* __restrict__ fcount) {
  int n = blockIdx.x * 256 + threadIdx.x;
  float v1 = 3.4e38f, v2 = 3.4e38f; int i1 = 0;
  #pragma unroll
  for (int kb = 0; kb < KBLK; ++kb) {
    float b1 = pv1[n * KBLK + kb]; int b1i = pi1[n * KBLK + kb];
    float b2 = pv2[n * KBLK + kb];
    bool  bw = (b1 < v1) || (b1 == v1 && b1i < i1);
    float lose = bw ? v1 : b1;
    float wv2  = bw ? b2 : v2;
    v2 = fminf(wv2, lose);
    if (bw) { v1 = b1; i1 = b1i; }
  }
  idx[n] = i1;
  float thr = KAPPA * sqrtf(fmaxf(v1 + vnorm[n], 0.f)) + 1e-5f;
  if (v2 - v1 < thr) {
    int s = atomicAdd(fcount, 1);
    flist[s] = n;                      // s < NVEC == FCAP always
  }
}

// ---------------------------------------------------------------------------
// fb_scan_t: exact f32 rescan for flagged vectors using transposed codebook.
// Block = (chunk of 32 vectors) x (k-slice of 256 codes). Coalesced cbT
// loads; vsT[d][v] broadcast float4 reads; dot[32] register accumulators.
// grid = 256 chunk-slots x FKS slices = 8192 blocks (inactive exit fast).
// ---------------------------------------------------------------------------
__global__ __launch_bounds__(256) void fb_scan_t(
    const float* __restrict__ cbT, const float* __restrict__ cc,
    const float* __restrict__ resid, const int* __restrict__ flist,
    const int* __restrict__ fcount,
    float* __restrict__ fpv, int* __restrict__ fpi) {
  __shared__ float vsT[DIM][36];           // [d][v], pad 36 (float4-aligned)
  __shared__ float mv[32][4];
  __shared__ int   mi[32][4];
  const int cnt = min(*fcount, FCAP);
  const int ks = blockIdx.x & (FKS - 1);
  const int chunk = blockIdx.x >> 5;
  if (chunk * 32 >= cnt) return;
  const int nv = min(32, cnt - chunk * 32);
  const int t = threadIdx.x;
  const int w = t >> 6, l = t & 63;

  #pragma unroll 4
  for (int v = 0; v < 32; ++v) {
    int s = chunk * 32 + v;
    int n = flist[s < cnt ? s : chunk * 32];
    vsT[t][v] = resid[(size_t)n * DIM + t];   // coalesced per v
  }
  __syncthreads();

  const int k = ks * 256 + t;
  const float cn = cc[k];
  float dot[32];
  #pragma unroll
  for (int v = 0; v < 32; ++v) dot[v] = 0.f;

  #pragma unroll 4
  for (int d = 0; d < DIM; ++d) {
    float cv = cbT[(size_t)d * NCODE + k];    // coalesced dword
    #pragma unroll
    for (int vq = 0; vq < 8; ++vq) {
      f4 a = *(const f4*)&vsT[d][vq * 4];     // broadcast, conflict-free
      dot[vq * 4 + 0] = fmaf(cv, a[0], dot[vq * 4 + 0]);
      dot[vq * 4 + 1] = fmaf(cv, a[1], dot[vq * 4 + 1]);
      dot[vq * 4 + 2] = fmaf(cv, a[2], dot[vq * 4 + 2]);
      dot[vq * 4 + 3] = fmaf(cv, a[3], dot[vq * 4 + 3]);
    }
  }

  // per-vector argmin: wave butterfly (codes ascend with lane), 4-wave merge
  #pragma unroll
  for (int v = 0; v < 32; ++v) {
    float bv = fmaf(-2.f, dot[v], cn);
    int   bi = k;
    #pragma unroll
    for (int m = 1; m < 64; m <<= 1) {
      float qv = __shfl_xor(bv, m);
      int   qi = __shfl_xor(bi, m);
      if (qv < bv || (qv == bv && qi < bi)) { bv = qv; bi = qi; }
    }
    if (l == 0) { mv[v][w] = bv; mi[v][w] = bi; }
  }
  __syncthreads();
  if (t < 32) {
    float bv = mv[t][0]; int bi = mi[t][0];
    #pragma unroll
    for (int ww = 1; ww < 4; ++ww) {
      float qv = mv[t][ww]; int qi = mi[t][ww];
      if (qv < bv || (qv == bv && qi < bi)) { bv = qv; bi = qi; }
    }
    if (t < nv) {
      fpv[(size_t)(chunk * 32 + t) * FKS + ks] = bv;
      fpi[(size_t)(chunk * 32 + t) * FKS + ks] = bi;
    }
  }
}

__global__ __launch_bounds__(256) void fb_merge(
    const float* __restrict__ fpv, const int* __restrict__ fpi,
    const int* __restrict__ flist, const int* __restrict__ fcount,
    int* __restrict__ idx) {
  int s = blockIdx.x * 256 + threadIdx.x;
  int cnt = min(*fcount, FCAP);
  if (s >= cnt) return;
  float v1 = 3.4e38f; int i1 = 0;
  #pragma unroll 8
  for (int kb = 0; kb < FKS; ++kb) {
    float b = fpv[(size_t)s * FKS + kb]; int b1i = fpi[(size_t)s * FKS + kb];
    if (b < v1 || (b == v1 && b1i < i1)) { v1 = b; i1 = b1i; }
  }
  idx[flist[s]] = i1;
}

// ---------------------------------------------------------------------------
// update: resid -= cb[idx]; rb = bf16(resid); rsum; code out as float.
// ---------------------------------------------------------------------------
__global__ __launch_bounds__(256) void update_kernel(
    const float* __restrict__ cb, const int* __restrict__ idx,
    float* __restrict__ resid, unsigned short* __restrict__ rb,
    float* __restrict__ rsum_out, float* __restrict__ codes_out, int depth) {
  int n    = blockIdx.x * 4 + (threadIdx.x >> 6);
  int lane = threadIdx.x & 63;
  int bi   = idx[n];
  float4 q = *(const float4*)&cb[(size_t)bi * DIM + lane * 4];
  float4 r = *(float4*)&resid[(size_t)n * DIM + lane * 4];
  r.x -= q.x; r.y -= q.y; r.z -= q.z; r.w -= q.w;
  *(float4*)&resid[(size_t)n * DIM + lane * 4] = r;
  b4 hv; hv[0] = (short)f2bf(r.x); hv[1] = (short)f2bf(r.y);
  hv[2] = (short)f2bf(r.z); hv[3] = (short)f2bf(r.w);
  *(b4*)&rb[(size_t)n * DIM + lane * 4] = hv;
  float s2 = r.x * r.x + r.y * r.y + r.z * r.z + r.w * r.w;
  #pragma unroll
  for (int off = 32; off > 0; off >>= 1) s2 += __shfl_down(s2, off, 64);
  if (lane == 0) {
    rsum_out[n] = s2;
    codes_out[n * DEPTH + depth] = (float)bi;
  }
}

// ---------------------------------------------------------------------------
// finalize: quants = x - resid (in place); block 0 reduces commitment loss.
// ---------------------------------------------------------------------------
__global__ __launch_bounds__(256) void finalize(const float* __restrict__ x,
                                                float* __restrict__ out,
                                                const float* __restrict__ rsumL) {
  int i = blockIdx.x * blockDim.x + threadIdx.x;
  float4 r  = *(float4*)&out[(size_t)i * 4];
  float4 xv = *(const float4*)&x[(size_t)i * 4];
  float4 o;
  o.x = xv.x - r.x; o.y = xv.y - r.y; o.z = xv.z - r.z; o.w = xv.w - r.w;
  *(float4*)&out[(size_t)i * 4] = o;

  if (blockIdx.x == 0) {
    __shared__ float sm[256];
    float s = 0.f;
    for (int j = threadIdx.x; j < DEPTH * NVEC; j += 256) s += rsumL[j];
    sm[threadIdx.x] = s;
    __syncthreads();
    for (int off = 128; off > 0; off >>= 1) {
      if (threadIdx.x < off) sm[threadIdx.x] += sm[threadIdx.x + off];
      __syncthreads();
    }
    if (threadIdx.x == 0)
      out[NVEC * DIM] = sm[0] / (float)DEPTH / (float)(NVEC * DIM);
  }
}

// ---------------------------------------------------------------------------
extern "C" void kernel_launch(void* const* d_in, const int* in_sizes, int n_in,
                              void* d_out, int out_size, void* d_ws, size_t ws_size,
                              hipStream_t stream) {
  const float* x  = (const float*)d_in[0];
  const float* cb = (const float*)d_in[1];
  float* out = (float*)d_out;
  char*  wsb = (char*)d_ws;

  // ws layout (~20 MB, under the proven 22.3 MB)
  unsigned short* cbh = (unsigned short*)(wsb);                 // 4 MB (per-depth)
  unsigned short* rb  = (unsigned short*)(wsb + 4194304);       // 4 MB
  float* cbT   = (float*)(wsb + 8388608);                       // 8 MB (per-depth)
  float* cc    = (float*)(wsb + 16777216);                      // 128 KB
  float* cchat = (float*)(wsb + 16908288);                      // 128 KB
  float* pv1   = (float*)(wsb + 17039360);                      // 512 KB
  int*   pi1   = (int*)  (wsb + 17563648);                      // 512 KB
  float* pv2   = (float*)(wsb + 18087936);                      // 512 KB
  float* rsum  = (float*)(wsb + 18612224);                      // 160 KB
  int*   idx   = (int*)  (wsb + 18776064);                      // 32 KB
  int*   flist = (int*)  (wsb + 18808832);                      // 32 KB
  int*   fcount= (int*)  (wsb + 18841600);                      // 256 B
  float* fpv   = (float*)(wsb + 18874368);                      // 1 MB
  int*   fpi   = (int*)  (wsb + 19922944);                      // 1 MB

  float* resid     = out;                    // quants region doubles as resid
  float* codes_out = out + NVEC * DIM + 1;

  prep_norms<<<(DEPTH * NCODE) / 4, 256, 0, stream>>>(cb, cc, cchat);
  init_kernel<<<NVEC / 4, 256, 0, stream>>>(x, resid, rb, rsum);

  for (int d = 0; d < DEPTH; ++d) {
    const size_t cbo = (size_t)d * NCODE * DIM;
    prep_depth<<<512, 256, 0, stream>>>(cb + cbo, cbh, cbT);
    coarse_kernel<<<(NVEC / 128) * KBLK, 256, 0, stream>>>(
        rb, cbh, cchat + d * NCODE, pv1, pi1, pv2);
    hipMemsetAsync(fcount, 0, 4, stream);
    merge_kernel<<<NVEC / 256, 256, 0, stream>>>(
        pv1, pi1, pv2, rsum + d * NVEC, idx, flist, fcount);
    fb_scan_t<<<256 * FKS, 256, 0, stream>>>(
        cbT, cc + d * NCODE, resid, flist, fcount, fpv, fpi);
    fb_merge<<<FCAP / 256, 256, 0, stream>>>(fpv, fpi, flist, fcount, idx);
    update_kernel<<<NVEC / 4, 256, 0, stream>>>(
        cb + cbo, idx, resid, rb, rsum + (d + 1) * NVEC, codes_out, d);
  }
  finalize<<<(NVEC * DIM / 4) / 256, 256, 0, stream>>>(x, out, rsum + NVEC);
}